// Round 8
// baseline (9936.341 us; speedup 1.0000x reference)
//
#include <hip/hip_runtime.h>

// ---------- types / helpers ----------
typedef short short8 __attribute__((ext_vector_type(8)));
typedef __bf16 bf16x8 __attribute__((ext_vector_type(8)));
typedef float f32x4 __attribute__((ext_vector_type(4)));
typedef float f32x4v __attribute__((ext_vector_type(4)));
typedef unsigned short u16x4 __attribute__((ext_vector_type(4)));
typedef unsigned long long u64;

__device__ __forceinline__ unsigned short f2b(float f) {
  unsigned x = __builtin_bit_cast(unsigned, f);
  x = x + 0x7fffu + ((x >> 16) & 1u);   // RNE (finite inputs)
  return (unsigned short)(x >> 16);
}
__device__ __forceinline__ float b2f(unsigned short u) {
  unsigned x = ((unsigned)u) << 16;
  return __builtin_bit_cast(float, x);
}
__device__ __forceinline__ f32x4 mfma16(short8 a, short8 b, f32x4 c) {
  return __builtin_amdgcn_mfma_f32_16x16x32_bf16(
      __builtin_bit_cast(bf16x8, a), __builtin_bit_cast(bf16x8, b), c, 0, 0, 0);
}
typedef const __attribute__((address_space(1))) void* gas_p;
typedef __attribute__((address_space(3))) void* las_p;
__device__ __forceinline__ void gload_lds16(const void* g, void* l) {
  __builtin_amdgcn_global_load_lds((gas_p)g, (las_p)l, 16, 0, 0);
}

#define NREG 512   // rotating exchange regions (16 MB window >> 4 MB L2)

// ---------- conversion kernels ----------
__global__ __launch_bounds__(256) void k_cvt_bf16(const float* __restrict__ in,
                                                  unsigned short* __restrict__ out,
                                                  int n4) {
  int i = blockIdx.x * 256 + threadIdx.x;
  if (i >= n4) return;
  f32x4v v = *(const f32x4v*)(in + (size_t)i * 4);
  u16x4 o;
  o[0] = f2b(v[0]); o[1] = f2b(v[1]); o[2] = f2b(v[2]); o[3] = f2b(v[3]);
  *(u16x4*)(out + (size_t)i * 4) = o;
}

// seed region 0 with tag0|bf16(h0); other regions self-invalidate via tags
__global__ __launch_bounds__(256) void k_init_hx(const float* __restrict__ h0,
                                                 unsigned int* __restrict__ hxbig) {
  int i = blockIdx.x * 256 + threadIdx.x;
  if (i < 8192) hxbig[i] = (unsigned int)f2b(h0[i]);
}

// flags2[i][g][w]: finisher wave w of WG g announces "h_i drained to L3".
// Row 0 seeded ready (h_0 comes from init).
__global__ __launch_bounds__(256) void k_init_flags2(unsigned int* __restrict__ flags2) {
  int i = blockIdx.x * 256 + threadIdx.x;
  if (i < 2048 * 128) flags2[i] = (i < 128) ? 1u : 0u;
}

// out[c][r] = bf16(in[r][c]);  R,C multiples of 32
__global__ __launch_bounds__(256) void k_transpose_bf16(const float* __restrict__ in,
                                                        unsigned short* __restrict__ out,
                                                        int R, int C) {
  __shared__ unsigned short tile[32][33];
  int c0 = blockIdx.x * 32, r0 = blockIdx.y * 32;
  int tx = threadIdx.x & 31, ty = threadIdx.x >> 5;
#pragma unroll
  for (int i = 0; i < 4; i++) {
    int r = ty + i * 8;
    tile[r][tx] = f2b(in[(size_t)(r0 + r) * C + c0 + tx]);
  }
  __syncthreads();
#pragma unroll
  for (int i = 0; i < 4; i++) {
    int rr = ty + i * 8;
    out[(size_t)(c0 + rr) * R + r0 + tx] = tile[tx][rr];
  }
}

// ---------- GEMM1: drive = silu(u)*silu(v)+w, feats = x@W_in + b_in ----------
__global__ __launch_bounds__(256) void k_gemm_drive(const unsigned short* __restrict__ xb,
                                                    const unsigned short* __restrict__ WinT,
                                                    const float* __restrict__ b_in,
                                                    unsigned short* __restrict__ drive) {
  __shared__ unsigned short At[128 * 32];
  __shared__ unsigned short Bt[3][64 * 32];
  const int tid = threadIdx.x;
  const int w = tid >> 6, l = tid & 63;
  const int wm = w >> 1, wn = w & 1;
  const int lr = l & 15, lk = (l >> 4) * 8;
  const int m0 = blockIdx.x * 128;
  const int j0 = blockIdx.y * 64;
  f32x4 acc[3][4][2];
#pragma unroll
  for (int s = 0; s < 3; s++)
#pragma unroll
    for (int mi = 0; mi < 4; mi++)
#pragma unroll
      for (int ni = 0; ni < 2; ni++)
#pragma unroll
        for (int e = 0; e < 4; e++) acc[s][mi][ni][e] = 0.f;

  const int sr = tid >> 2;
  const int skb = (tid & 3) * 8;
  for (int kt = 0; kt < 32; kt++) {
    const int k0 = kt * 32;
    gload_lds16(xb + (size_t)(m0 + sr) * 1024 + k0 + skb, &At[w * 512]);
    gload_lds16(xb + (size_t)(m0 + 64 + sr) * 1024 + k0 + skb, &At[2048 + w * 512]);
#pragma unroll
    for (int s = 0; s < 3; s++)
      gload_lds16(WinT + (size_t)(s * 1024 + j0 + sr) * 1024 + k0 + skb, &Bt[s][w * 512]);
    __syncthreads();
    short8 Af[4], Bf[3][2];
#pragma unroll
    for (int mi = 0; mi < 4; mi++)
      Af[mi] = *(const short8*)&At[(wm * 64 + mi * 16 + lr) * 32 + lk];
#pragma unroll
    for (int s = 0; s < 3; s++)
#pragma unroll
      for (int ni = 0; ni < 2; ni++)
        Bf[s][ni] = *(const short8*)&Bt[s][(wn * 32 + ni * 16 + lr) * 32 + lk];
#pragma unroll
    for (int s = 0; s < 3; s++)
#pragma unroll
      for (int mi = 0; mi < 4; mi++)
#pragma unroll
        for (int ni = 0; ni < 2; ni++)
          acc[s][mi][ni] = mfma16(Af[mi], Bf[s][ni], acc[s][mi][ni]);
    __syncthreads();
  }
#pragma unroll
  for (int ni = 0; ni < 2; ni++) {
    const int c = j0 + wn * 32 + ni * 16 + lr;
    const float bu = b_in[c], bv = b_in[1024 + c], bw = b_in[2048 + c];
#pragma unroll
    for (int mi = 0; mi < 4; mi++) {
      const int r0 = m0 + wm * 64 + mi * 16 + (l >> 4) * 4;
#pragma unroll
      for (int e = 0; e < 4; e++) {
        float u = acc[0][mi][ni][e] + bu;
        float v = acc[1][mi][ni][e] + bv;
        float wv = acc[2][mi][ni][e] + bw;
        float su = u / (1.f + __expf(-u));
        float sv = v / (1.f + __expf(-v));
        drive[(size_t)(r0 + e) * 1024 + c] = f2b(su * sv + wv);
      }
    }
  }
}

// ---------- persistent scan kernel v8 ----------
// 64 WGs x 1024 threads. WG g owns h-features [16g,16g+16).
// Exchange: tagged words ((tag<<16)|bf16, tag=i) in ROTATING regions
// hxbig[i&511][8192]. Producers publish with agent-scope stores (to L3),
// drain with their OWN s_waitcnt vmcnt(0), then set per-wave flags (uncached).
// Consumers: flag-gate (one u64 load covers both waves of all 64 WGs), then
// PLAIN CACHED reads of the region - cold in L1/L2 (512-step rotation evicts)
// => must fill from L3 => fresh. Tags backstop any stale line (uncached
// fallback per word). Software-pipelined 2-barrier loop:
//   phase A: [pollers fetch h_i -> tile] || [finishers compute h_i from
//            buf(i-1), publish, flag] ; bar
//   phase B: MFMA tile(i) -> buf(i) ; bar
__global__ __launch_bounds__(1024, 4) void k_scan(const unsigned short* __restrict__ WgT,
                                                  const unsigned short* __restrict__ WrT,
                                                  const float* __restrict__ b_gate,
                                                  const float* __restrict__ b_rec,
                                                  const unsigned short* __restrict__ drive,
                                                  unsigned int* __restrict__ hxbig,
                                                  unsigned int* __restrict__ flags2,
                                                  unsigned short* __restrict__ hs,
                                                  float* __restrict__ final_h) {
  const int g = blockIdx.x;           // 0..63
  const int tid = threadIdx.x;        // 0..1023
  const int w = tid >> 6, l = tid & 63;

  __shared__ unsigned short tile[8][1024];   // h_i (bf16), XOR-swizzled rows
  __shared__ float buf[4][8][48];            // per-K-quarter partial sums

  // ---- MFMA-wave setup (w<12): weights -> registers, 32 VGPR/wave ----
  const int mat = w >> 2, kq = w & 3;
  const int c = l & 15, ko = l >> 4;
  const bool av = c < 8;
  const unsigned swzA = (unsigned)((c & 7) << 4);
  short8 Breg[8];
  if (w < 12) {
    const unsigned short* WT = (mat == 2) ? WrT : WgT;
    const int rowbase = ((mat == 1) ? 1024 : 0) + g * 16;
#pragma unroll
    for (int ks = 0; ks < 8; ++ks)
      Breg[ks] = *(const short8*)&WT[(size_t)(rowbase + c) * 1024 +
                                     kq * 256 + ks * 32 + ko * 8];
  }

  // ---- poller setup (tid>=768) ----
  const bool isld = tid >= 768;
  const int L = tid & 255;
  const int lb = L >> 5, lc = L & 31;        // batch row, feature chunk
  char* ldsrow = (char*)&tile[0][0] + (size_t)(lb & 7) * 2048;
  const unsigned swzL = (unsigned)((lb & 7) << 4);

  // ---- finisher setup (tid<128, waves 0-1) ----
  const bool isfin = tid < 128;
  const int fb = tid >> 4, ff = tid & 15;
  const int fcol = g * 16 + ff;
  float bgv = 0.f, bgt = 0.f, brc = 0.f;
  unsigned short dpf_next = 0;
  if (isfin) {
    bgv = b_gate[fcol]; bgt = b_gate[1024 + fcol]; brc = b_rec[fcol];
    dpf_next = drive[(size_t)(fb * 2048 + 0) * 1024 + fcol];  // for iter 1
  }

  for (int i = 0; i < 2048; ++i) {
    // ======== phase A ========
    if (isfin && i > 0) {
      // compute h_i from buf(i-1) and drive[i-1] (prefetched)
      const unsigned short dpf = dpf_next;
      const float gv = ((buf[0][fb][ff] + buf[1][fb][ff]) +
                        (buf[2][fb][ff] + buf[3][fb][ff])) + bgv;
      const float gt = ((buf[0][fb][16 + ff] + buf[1][fb][16 + ff]) +
                        (buf[2][fb][16 + ff] + buf[3][fb][16 + ff])) + bgt;
      const float rc = ((buf[0][fb][32 + ff] + buf[1][fb][32 + ff]) +
                        (buf[2][fb][32 + ff] + buf[3][fb][32 + ff])) + brc;
      const float sgv = 1.f / (1.f + __expf(-gv));
      const float sgt = 1.f / (1.f + __expf(-gt));
      const float gate = sgv * gt * sgt;  // sigmoid(gv) * silu(gt)
      const float nh = gate * rc + (1.f - gate) * b2f(dpf);
      const unsigned short nhb = f2b(nh);
      // publish tagged word to rotating region (agent scope -> L3)
      __hip_atomic_store(hxbig + (size_t)(i & (NREG - 1)) * 8192 + fb * 1024 + fcol,
                         (((unsigned)i) << 16) | (unsigned)nhb,
                         __ATOMIC_RELAXED, __HIP_MEMORY_SCOPE_AGENT);
      hs[(size_t)(fb * 2048 + (i - 1)) * 1024 + fcol] = nhb;
      // drain THIS wave's stores, then announce (flag visible => data at L3)
      asm volatile("s_waitcnt vmcnt(0)" ::: "memory");
      if ((tid & 63) == 0)
        __hip_atomic_store(flags2 + ((size_t)i * 64 + g) * 2 + (tid >> 6), 1u,
                           __ATOMIC_RELAXED, __HIP_MEMORY_SCOPE_AGENT);
      // prefetch drive[i] for the next finisher phase (latency hidden)
      dpf_next = drive[(size_t)(fb * 2048 + i) * 1024 + fcol];
      if (i == 2047) {  // epilogue h_2048 (no publish needed)
        asm volatile("s_waitcnt vmcnt(0)" ::: "memory");
      }
    }
    if (isld) {
      if (i > 0) {  // flag gate: one u64 load covers both waves of WG l
        const u64* fp = (const u64*)flags2 + (size_t)i * 64;
        for (;;) {
          u64 f = __hip_atomic_load(fp + l, __ATOMIC_RELAXED,
                                    __HIP_MEMORY_SCOPE_AGENT);
          if (__all(((unsigned)f != 0u) & ((unsigned)(f >> 32) != 0u))) break;
        }
      }
      asm volatile("" ::: "memory");  // no hoisting cached reads above the gate
      const u64* hb = (const u64*)(hxbig + (size_t)(i & (NREG - 1)) * 8192) +
                      (lb * 512 + lc);
      const unsigned tg = (unsigned)i;
      u64 v[16];
#pragma unroll
      for (int q = 0; q < 16; ++q) v[q] = hb[q * 32];   // PLAIN CACHED loads
      unsigned pend = 0;
#pragma unroll
      for (int q = 0; q < 16; ++q) {
        unsigned lo = (unsigned)v[q], hi = (unsigned)(v[q] >> 32);
        if (((lo >> 16) == tg) & ((hi >> 16) == tg)) {
          unsigned pk = __builtin_amdgcn_perm(hi, lo, 0x05040100u);
          *(unsigned*)(ldsrow + (((unsigned)(q * 128 + lc * 4)) ^ swzL)) = pk;
        } else pend |= 1u << q;
      }
      while (pend) {  // rare: stale cached line -> uncached per-word fallback
        __builtin_amdgcn_s_sleep(1);
        unsigned np = 0;
#pragma unroll
        for (int q = 0; q < 16; ++q)
          if ((pend >> q) & 1) {
            u64 vv = __hip_atomic_load(hb + q * 32, __ATOMIC_RELAXED,
                                       __HIP_MEMORY_SCOPE_AGENT);
            unsigned lo = (unsigned)vv, hi = (unsigned)(vv >> 32);
            if (((lo >> 16) == tg) & ((hi >> 16) == tg)) {
              unsigned pk = __builtin_amdgcn_perm(hi, lo, 0x05040100u);
              *(unsigned*)(ldsrow + (((unsigned)(q * 128 + lc * 4)) ^ swzL)) = pk;
            } else np |= 1u << q;
          }
        pend = np;
      }
    }
    __syncthreads();   // tile(i) complete; buf(i-1) consumed

    // ======== phase B: MFMA tile(i) -> buf(i) ========
    if (w < 12) {
      const char* base = (const char*)&tile[0][0] + (size_t)c * 2048;
      f32x4 a0, a1;
#pragma unroll
      for (int e = 0; e < 4; ++e) { a0[e] = 0.f; a1[e] = 0.f; }
#pragma unroll
      for (int ks = 0; ks < 8; ++ks) {
        const unsigned off = ((unsigned)(kq * 512 + ks * 64 + ko * 16)) ^ swzA;
        short8 Af;
#pragma unroll
        for (int e = 0; e < 8; ++e) Af[e] = 0;
        if (av) Af = *(const short8*)(base + off);
        if (ks & 1) a1 = mfma16(Af, Breg[ks], a1);
        else        a0 = mfma16(Af, Breg[ks], a0);
      }
      if (l < 32) {
        const int r0 = ko * 4;
#pragma unroll
        for (int e = 0; e < 4; ++e)
          buf[kq][r0 + e][mat * 16 + c] = a0[e] + a1[e];
      }
    }
    __syncthreads();   // buf(i) complete; tile free for i+1
  }

  // ---- epilogue: h_2048 from buf(2047) and drive[2047] ----
  if (isfin) {
    const float gv = ((buf[0][fb][ff] + buf[1][fb][ff]) +
                      (buf[2][fb][ff] + buf[3][fb][ff])) + bgv;
    const float gt = ((buf[0][fb][16 + ff] + buf[1][fb][16 + ff]) +
                      (buf[2][fb][16 + ff] + buf[3][fb][16 + ff])) + bgt;
    const float rc = ((buf[0][fb][32 + ff] + buf[1][fb][32 + ff]) +
                      (buf[2][fb][32 + ff] + buf[3][fb][32 + ff])) + brc;
    const float sgv = 1.f / (1.f + __expf(-gv));
    const float sgt = 1.f / (1.f + __expf(-gt));
    const float gate = sgv * gt * sgt;
    const float nh = gate * rc + (1.f - gate) * b2f(dpf_next);
    const unsigned short nhb = f2b(nh);
    hs[(size_t)(fb * 2048 + 2047) * 1024 + fcol] = nhb;
    final_h[fb * 1024 + fcol] = nh;
  }
}

// ---------- GEMM3: out = hs @ W_out + b_out ----------
__global__ __launch_bounds__(256) void k_gemm_out(const unsigned short* __restrict__ hs,
                                                  const unsigned short* __restrict__ WoT,
                                                  const float* __restrict__ b_out,
                                                  float* __restrict__ out) {
  __shared__ unsigned short At[128 * 32];
  __shared__ unsigned short Bt[128 * 32];
  const int tid = threadIdx.x;
  const int w = tid >> 6, l = tid & 63;
  const int wm = w >> 1, wn = w & 1;
  const int lr = l & 15, lk = (l >> 4) * 8;
  const int m0 = blockIdx.x * 128;
  const int n0 = blockIdx.y * 128;
  f32x4 acc[4][4];
#pragma unroll
  for (int mi = 0; mi < 4; mi++)
#pragma unroll
    for (int ni = 0; ni < 4; ni++)
#pragma unroll
      for (int e = 0; e < 4; e++) acc[mi][ni][e] = 0.f;

  const int sr = tid >> 2;
  const int skb = (tid & 3) * 8;
  for (int kt = 0; kt < 32; kt++) {
    const int k0 = kt * 32;
    gload_lds16(hs + (size_t)(m0 + sr) * 1024 + k0 + skb, &At[w * 512]);
    gload_lds16(hs + (size_t)(m0 + 64 + sr) * 1024 + k0 + skb, &At[2048 + w * 512]);
    gload_lds16(WoT + (size_t)(n0 + sr) * 1024 + k0 + skb, &Bt[w * 512]);
    gload_lds16(WoT + (size_t)(n0 + 64 + sr) * 1024 + k0 + skb, &Bt[2048 + w * 512]);
    __syncthreads();
    short8 Af[4], Bf[4];
#pragma unroll
    for (int mi = 0; mi < 4; mi++)
      Af[mi] = *(const short8*)&At[(wm * 64 + mi * 16 + lr) * 32 + lk];
#pragma unroll
    for (int ni = 0; ni < 4; ni++)
      Bf[ni] = *(const short8*)&Bt[(wn * 64 + ni * 16 + lr) * 32 + lk];
#pragma unroll
    for (int mi = 0; mi < 4; mi++)
#pragma unroll
      for (int ni = 0; ni < 4; ni++)
        acc[mi][ni] = mfma16(Af[mi], Bf[ni], acc[mi][ni]);
    __syncthreads();
  }
#pragma unroll
  for (int ni = 0; ni < 4; ni++) {
    const int c = n0 + wn * 64 + ni * 16 + lr;
    const float bo = b_out[c];
#pragma unroll
    for (int mi = 0; mi < 4; mi++) {
      const int r0 = m0 + wm * 64 + mi * 16 + (l >> 4) * 4;
#pragma unroll
      for (int e = 0; e < 4; e++)
        out[(size_t)(r0 + e) * 1024 + c] = acc[mi][ni][e] + bo;
    }
  }
}

// ---------- launch ----------
extern "C" void kernel_launch(void* const* d_in, const int* in_sizes, int n_in,
                              void* d_out, int out_size, void* d_ws, size_t ws_size,
                              hipStream_t stream) {
  const float* x      = (const float*)d_in[0];
  const float* h0     = (const float*)d_in[1];
  const float* W_in   = (const float*)d_in[2];
  const float* b_in   = (const float*)d_in[3];
  const float* W_gate = (const float*)d_in[4];
  const float* b_gate = (const float*)d_in[5];
  const float* W_rec  = (const float*)d_in[6];
  const float* b_rec  = (const float*)d_in[7];
  const float* W_out  = (const float*)d_in[8];
  const float* b_out  = (const float*)d_in[9];
  float* outp = (float*)d_out;

  size_t off = 0;
  auto alloc = [&](size_t bytes) {
    void* p = (char*)d_ws + off;
    off += (bytes + 255) & ~(size_t)255;
    return p;
  };
  unsigned short* xb    = (unsigned short*)alloc((size_t)16777216 * 2);
  unsigned short* WinT  = (unsigned short*)alloc((size_t)3072 * 1024 * 2);
  unsigned short* WgT   = (unsigned short*)alloc((size_t)2048 * 1024 * 2);
  unsigned short* WrT   = (unsigned short*)alloc((size_t)1024 * 1024 * 2);
  unsigned short* WoT   = (unsigned short*)alloc((size_t)1024 * 1024 * 2);
  unsigned short* drive = (unsigned short*)alloc((size_t)16777216 * 2);
  unsigned short* hs    = (unsigned short*)alloc((size_t)16777216 * 2);
  unsigned int*   hxbig = (unsigned int*)alloc((size_t)NREG * 8192 * 4);   // 16MB
  unsigned int*   flags2= (unsigned int*)alloc((size_t)2048 * 128 * 4);    // 1MB

  // conversions / init
  k_cvt_bf16<<<16384, 256, 0, stream>>>(x, xb, 4194304);
  k_transpose_bf16<<<dim3(96, 32), 256, 0, stream>>>(W_in, WinT, 1024, 3072);
  k_transpose_bf16<<<dim3(64, 32), 256, 0, stream>>>(W_gate, WgT, 1024, 2048);
  k_transpose_bf16<<<dim3(32, 32), 256, 0, stream>>>(W_rec, WrT, 1024, 1024);
  k_transpose_bf16<<<dim3(32, 32), 256, 0, stream>>>(W_out, WoT, 1024, 1024);
  k_init_hx<<<32, 256, 0, stream>>>(h0, hxbig);
  k_init_flags2<<<1024, 256, 0, stream>>>(flags2);

  // drive = silu(u)*silu(v)+w
  k_gemm_drive<<<dim3(128, 16), 256, 0, stream>>>(xb, WinT, b_in, drive);
  // sequential recurrence (rotating cached exchange + uncached flags)
  k_scan<<<64, 1024, 0, stream>>>(WgT, WrT, b_gate, b_rec, drive, hxbig, flags2,
                                  hs, outp + 16777216);
  // out = hs @ W_out + b_out
  k_gemm_out<<<dim3(128, 8), 256, 0, stream>>>(hs, WoT, b_out, outp);
}

// Round 9
// 7605.906 us; speedup vs baseline: 1.3064x; 1.3064x over previous
//
#include <hip/hip_runtime.h>

// ---------- types / helpers ----------
typedef short short8 __attribute__((ext_vector_type(8)));
typedef __bf16 bf16x8 __attribute__((ext_vector_type(8)));
typedef float f32x4 __attribute__((ext_vector_type(4)));
typedef float f32x4v __attribute__((ext_vector_type(4)));
typedef unsigned short u16x4 __attribute__((ext_vector_type(4)));
typedef unsigned long long u64;

__device__ __forceinline__ unsigned short f2b(float f) {
  unsigned x = __builtin_bit_cast(unsigned, f);
  x = x + 0x7fffu + ((x >> 16) & 1u);   // RNE (finite inputs)
  return (unsigned short)(x >> 16);
}
__device__ __forceinline__ float b2f(unsigned short u) {
  unsigned x = ((unsigned)u) << 16;
  return __builtin_bit_cast(float, x);
}
__device__ __forceinline__ f32x4 mfma16(short8 a, short8 b, f32x4 c) {
  return __builtin_amdgcn_mfma_f32_16x16x32_bf16(
      __builtin_bit_cast(bf16x8, a), __builtin_bit_cast(bf16x8, b), c, 0, 0, 0);
}
typedef const __attribute__((address_space(1))) void* gas_p;
typedef __attribute__((address_space(3))) void* las_p;
__device__ __forceinline__ void gload_lds16(const void* g, void* l) {
  __builtin_amdgcn_global_load_lds((gas_p)g, (las_p)l, 16, 0, 0);
}

// ---------- conversion kernels ----------
__global__ __launch_bounds__(256) void k_cvt_bf16(const float* __restrict__ in,
                                                  unsigned short* __restrict__ out,
                                                  int n4) {
  int i = blockIdx.x * 256 + threadIdx.x;
  if (i >= n4) return;
  f32x4v v = *(const f32x4v*)(in + (size_t)i * 4);
  u16x4 o;
  o[0] = f2b(v[0]); o[1] = f2b(v[1]); o[2] = f2b(v[2]); o[3] = f2b(v[3]);
  *(u16x4*)(out + (size_t)i * 4) = o;
}

// hx[0][i] = tag0 | bf16(h0[i]);  hx[1][i] = 0
__global__ __launch_bounds__(256) void k_init_hx(const float* __restrict__ h0,
                                                 unsigned int* __restrict__ hx) {
  int i = blockIdx.x * 256 + threadIdx.x;
  if (i >= 8192) return;
  hx[i] = (unsigned int)f2b(h0[i]);
  hx[8192 + i] = 0u;
}

// out[c][r] = bf16(in[r][c]);  R,C multiples of 32
__global__ __launch_bounds__(256) void k_transpose_bf16(const float* __restrict__ in,
                                                        unsigned short* __restrict__ out,
                                                        int R, int C) {
  __shared__ unsigned short tile[32][33];
  int c0 = blockIdx.x * 32, r0 = blockIdx.y * 32;
  int tx = threadIdx.x & 31, ty = threadIdx.x >> 5;
#pragma unroll
  for (int i = 0; i < 4; i++) {
    int r = ty + i * 8;
    tile[r][tx] = f2b(in[(size_t)(r0 + r) * C + c0 + tx]);
  }
  __syncthreads();
#pragma unroll
  for (int i = 0; i < 4; i++) {
    int rr = ty + i * 8;
    out[(size_t)(c0 + rr) * R + r0 + tx] = tile[tx][rr];
  }
}

// ---------- GEMM1: drive = silu(u)*silu(v)+w, feats = x@W_in + b_in ----------
__global__ __launch_bounds__(256) void k_gemm_drive(const unsigned short* __restrict__ xb,
                                                    const unsigned short* __restrict__ WinT,
                                                    const float* __restrict__ b_in,
                                                    unsigned short* __restrict__ drive) {
  __shared__ unsigned short At[128 * 32];
  __shared__ unsigned short Bt[3][64 * 32];
  const int tid = threadIdx.x;
  const int w = tid >> 6, l = tid & 63;
  const int wm = w >> 1, wn = w & 1;
  const int lr = l & 15, lk = (l >> 4) * 8;
  const int m0 = blockIdx.x * 128;
  const int j0 = blockIdx.y * 64;
  f32x4 acc[3][4][2];
#pragma unroll
  for (int s = 0; s < 3; s++)
#pragma unroll
    for (int mi = 0; mi < 4; mi++)
#pragma unroll
      for (int ni = 0; ni < 2; ni++)
#pragma unroll
        for (int e = 0; e < 4; e++) acc[s][mi][ni][e] = 0.f;

  const int sr = tid >> 2;
  const int skb = (tid & 3) * 8;
  for (int kt = 0; kt < 32; kt++) {
    const int k0 = kt * 32;
    gload_lds16(xb + (size_t)(m0 + sr) * 1024 + k0 + skb, &At[w * 512]);
    gload_lds16(xb + (size_t)(m0 + 64 + sr) * 1024 + k0 + skb, &At[2048 + w * 512]);
#pragma unroll
    for (int s = 0; s < 3; s++)
      gload_lds16(WinT + (size_t)(s * 1024 + j0 + sr) * 1024 + k0 + skb, &Bt[s][w * 512]);
    __syncthreads();
    short8 Af[4], Bf[3][2];
#pragma unroll
    for (int mi = 0; mi < 4; mi++)
      Af[mi] = *(const short8*)&At[(wm * 64 + mi * 16 + lr) * 32 + lk];
#pragma unroll
    for (int s = 0; s < 3; s++)
#pragma unroll
      for (int ni = 0; ni < 2; ni++)
        Bf[s][ni] = *(const short8*)&Bt[s][(wn * 32 + ni * 16 + lr) * 32 + lk];
#pragma unroll
    for (int s = 0; s < 3; s++)
#pragma unroll
      for (int mi = 0; mi < 4; mi++)
#pragma unroll
        for (int ni = 0; ni < 2; ni++)
          acc[s][mi][ni] = mfma16(Af[mi], Bf[s][ni], acc[s][mi][ni]);
    __syncthreads();
  }
#pragma unroll
  for (int ni = 0; ni < 2; ni++) {
    const int c = j0 + wn * 32 + ni * 16 + lr;
    const float bu = b_in[c], bv = b_in[1024 + c], bw = b_in[2048 + c];
#pragma unroll
    for (int mi = 0; mi < 4; mi++) {
      const int r0 = m0 + wm * 64 + mi * 16 + (l >> 4) * 4;
#pragma unroll
      for (int e = 0; e < 4; e++) {
        float u = acc[0][mi][ni][e] + bu;
        float v = acc[1][mi][ni][e] + bv;
        float wv = acc[2][mi][ni][e] + bw;
        float su = u / (1.f + __expf(-u));
        float sv = v / (1.f + __expf(-v));
        drive[(size_t)(r0 + e) * 1024 + c] = f2b(su * sv + wv);
      }
    }
  }
}

// ---------- persistent scan kernel v9 = v4 + exchange-phase instrumentation ----------
// Structure byte-identical to R4 (best known: 6963 us): 64 WGs x 1024 thr,
// tagged hx[2][8192] exchange, relaxed agent-scope atomics, reg weights.
// NEW: wave 12 accumulates s_memrealtime ticks spent in the exchange phase
// (poll sweeps + LDS pack) over 2048 steps, then emits one 8B agent-scope
// store per 32 ticks into the dead xb region ->
//   T_wait_us_per_step = (WRITE_SIZE_KB - 98848) / 6400      (cap 10.5 ms)
__global__ __launch_bounds__(1024, 4) void k_scan(const unsigned short* __restrict__ WgT,
                                                  const unsigned short* __restrict__ WrT,
                                                  const float* __restrict__ b_gate,
                                                  const float* __restrict__ b_rec,
                                                  const unsigned short* __restrict__ drive,
                                                  unsigned int* __restrict__ hx,
                                                  unsigned short* __restrict__ hs,
                                                  float* __restrict__ final_h,
                                                  unsigned long long* __restrict__ dump) {
  const int g = blockIdx.x;           // 0..63
  const int tid = threadIdx.x;        // 0..1023
  const int w = tid >> 6, l = tid & 63;

  __shared__ unsigned short tile[8][1024];   // h_t (bf16), XOR-swizzled rows
  __shared__ float buf[4][8][48];            // per-K-quarter partial sums

  // ---- MFMA-wave setup (w<12): weights -> registers, 32 VGPR/wave ----
  const int mat = w >> 2, kq = w & 3;
  const int c = l & 15, ko = l >> 4;
  const bool av = c < 8;
  const unsigned swzA = (unsigned)((c & 7) << 4);
  short8 Breg[8];
  if (w < 12) {
    const unsigned short* WT = (mat == 2) ? WrT : WgT;
    const int rowbase = ((mat == 1) ? 1024 : 0) + g * 16;
#pragma unroll
    for (int ks = 0; ks < 8; ++ks)
      Breg[ks] = *(const short8*)&WT[(size_t)(rowbase + c) * 1024 +
                                     kq * 256 + ks * 32 + ko * 8];
  }

  // ---- poller setup (tid>=768) ----
  const bool isld = tid >= 768;
  const int L = tid & 255;
  const int lb = L >> 5, lc = L & 31;        // batch row, feature chunk
  char* ldsrow = (char*)&tile[0][0] + (size_t)(lb & 7) * 2048;
  const unsigned swzL = (unsigned)((lb & 7) << 4);

  // ---- finisher setup (tid<128) ----
  const bool isfin = tid < 128;
  const int fb = tid >> 4, ff = tid & 15;
  const int fcol = g * 16 + ff;
  float bgv = 0.f, bgt = 0.f, brc = 0.f;
  if (isfin) { bgv = b_gate[fcol]; bgt = b_gate[1024 + fcol]; brc = b_rec[fcol]; }

  u64 twait = 0;   // wave-12 uniform: total ticks in exchange phase

  for (int t = 0; t < 2048; ++t) {
    const int p = t & 1;
    unsigned short dpf = 0;
    if (isfin) dpf = drive[(size_t)(fb * 2048 + t) * 1024 + fcol];

    u64 t0 = 0;
    if (w == 12) t0 = __builtin_amdgcn_s_memrealtime();
    if (isld) {  // ---- poll h_t (tags == t), pack validated words to tile ----
      const unsigned tg = (unsigned)t;
      const u64* hb = (const u64*)(hx + (size_t)p * 8192) + (lb * 512 + lc);
      unsigned pend = 0xffffu;
      do {
        u64 v[16];
#pragma unroll
        for (int q = 0; q < 16; ++q)
          if ((pend >> q) & 1)
            v[q] = __hip_atomic_load(hb + q * 32, __ATOMIC_RELAXED,
                                     __HIP_MEMORY_SCOPE_AGENT);
        unsigned np = 0;
#pragma unroll
        for (int q = 0; q < 16; ++q)
          if ((pend >> q) & 1) {
            unsigned lo = (unsigned)v[q], hi = (unsigned)(v[q] >> 32);
            if (((lo >> 16) == tg) & ((hi >> 16) == tg)) {
              unsigned pk = __builtin_amdgcn_perm(hi, lo, 0x05040100u);
              *(unsigned*)(ldsrow + (((unsigned)(q * 128 + lc * 4)) ^ swzL)) = pk;
            } else np |= 1u << q;
          }
        pend = np;
      } while (pend);
    }
    if (w == 12) twait += __builtin_amdgcn_s_memrealtime() - t0;
    __syncthreads();   // tile(t) complete

    // ---- MFMA: 8 k-slices per wave, 2 independent chains ----
    if (w < 12) {
      const char* base = (const char*)&tile[0][0] + (size_t)c * 2048;
      f32x4 a0, a1;
#pragma unroll
      for (int e = 0; e < 4; ++e) { a0[e] = 0.f; a1[e] = 0.f; }
#pragma unroll
      for (int ks = 0; ks < 8; ++ks) {
        const unsigned off = ((unsigned)(kq * 512 + ks * 64 + ko * 16)) ^ swzA;
        short8 Af;
#pragma unroll
        for (int e = 0; e < 8; ++e) Af[e] = 0;
        if (av) Af = *(const short8*)(base + off);
        if (ks & 1) a1 = mfma16(Af, Breg[ks], a1);
        else        a0 = mfma16(Af, Breg[ks], a0);
      }
      if (l < 32) {
        const int r0 = ko * 4;     // ko in {0,1} for l<32 -> batches 0..7
#pragma unroll
        for (int e = 0; e < 4; ++e)
          buf[kq][r0 + e][mat * 16 + c] = a0[e] + a1[e];
      }
    }
    __syncthreads();   // buf complete; tile free for t+1

    // ---- finisher: K-quarter reduce + gate math + tagged publish ----
    if (isfin) {
      const float gv = ((buf[0][fb][ff] + buf[1][fb][ff]) +
                        (buf[2][fb][ff] + buf[3][fb][ff])) + bgv;
      const float gt = ((buf[0][fb][16 + ff] + buf[1][fb][16 + ff]) +
                        (buf[2][fb][16 + ff] + buf[3][fb][16 + ff])) + bgt;
      const float rc = ((buf[0][fb][32 + ff] + buf[1][fb][32 + ff]) +
                        (buf[2][fb][32 + ff] + buf[3][fb][32 + ff])) + brc;
      const float sgv = 1.f / (1.f + __expf(-gv));
      const float sgt = 1.f / (1.f + __expf(-gt));
      const float gate = sgv * gt * sgt;  // sigmoid(gv) * silu(gt)
      const float nh = gate * rc + (1.f - gate) * b2f(dpf);
      const unsigned short nhb = f2b(nh);
      __hip_atomic_store(hx + (size_t)(p ^ 1) * 8192 + fb * 1024 + fcol,
                         (((unsigned)(t + 1)) << 16) | (unsigned)nhb,
                         __ATOMIC_RELAXED, __HIP_MEMORY_SCOPE_AGENT);
      hs[(size_t)(fb * 2048 + t) * 1024 + fcol] = nhb;
      if (t == 2047) final_h[fb * 1024 + fcol] = nh;
    }
  }

  // ---- side-channel dump: one 8B sc1 store per 32 ticks of twait ----
  // per lane: n = twait/32/64 stores; per WG bytes = 64*n*8 = twait/4... 
  // total WRITE delta KB = 64WG * (twait/2) B /1024 = twait/32 KB
  if (w == 12) {
    u64 n = (twait >> 5) >> 6;          // stores per lane = twait/2048
    if (n > 1024) n = 1024;             // cap 0.5 MB/WG (T <= 1.05M ticks)
    unsigned long long* dp = dump + (size_t)g * 65536 + l;
    for (u64 i = 0; i < n; ++i)
      __hip_atomic_store(dp + i * 64, twait, __ATOMIC_RELAXED,
                         __HIP_MEMORY_SCOPE_AGENT);
  }
}

// ---------- GEMM3: out = hs @ W_out + b_out ----------
__global__ __launch_bounds__(256) void k_gemm_out(const unsigned short* __restrict__ hs,
                                                  const unsigned short* __restrict__ WoT,
                                                  const float* __restrict__ b_out,
                                                  float* __restrict__ out) {
  __shared__ unsigned short At[128 * 32];
  __shared__ unsigned short Bt[128 * 32];
  const int tid = threadIdx.x;
  const int w = tid >> 6, l = tid & 63;
  const int wm = w >> 1, wn = w & 1;
  const int lr = l & 15, lk = (l >> 4) * 8;
  const int m0 = blockIdx.x * 128;
  const int n0 = blockIdx.y * 128;
  f32x4 acc[4][4];
#pragma unroll
  for (int mi = 0; mi < 4; mi++)
#pragma unroll
    for (int ni = 0; ni < 4; ni++)
#pragma unroll
      for (int e = 0; e < 4; e++) acc[mi][ni][e] = 0.f;

  const int sr = tid >> 2;
  const int skb = (tid & 3) * 8;
  for (int kt = 0; kt < 32; kt++) {
    const int k0 = kt * 32;
    gload_lds16(hs + (size_t)(m0 + sr) * 1024 + k0 + skb, &At[w * 512]);
    gload_lds16(hs + (size_t)(m0 + 64 + sr) * 1024 + k0 + skb, &At[2048 + w * 512]);
    gload_lds16(WoT + (size_t)(n0 + sr) * 1024 + k0 + skb, &Bt[w * 512]);
    gload_lds16(WoT + (size_t)(n0 + 64 + sr) * 1024 + k0 + skb, &Bt[2048 + w * 512]);
    __syncthreads();
    short8 Af[4], Bf[4];
#pragma unroll
    for (int mi = 0; mi < 4; mi++)
      Af[mi] = *(const short8*)&At[(wm * 64 + mi * 16 + lr) * 32 + lk];
#pragma unroll
    for (int ni = 0; ni < 4; ni++)
      Bf[ni] = *(const short8*)&Bt[(wn * 64 + ni * 16 + lr) * 32 + lk];
#pragma unroll
    for (int mi = 0; mi < 4; mi++)
#pragma unroll
      for (int ni = 0; ni < 4; ni++)
        acc[mi][ni] = mfma16(Af[mi], Bf[ni], acc[mi][ni]);
    __syncthreads();
  }
#pragma unroll
  for (int ni = 0; ni < 4; ni++) {
    const int c = n0 + wn * 64 + ni * 16 + lr;
    const float bo = b_out[c];
#pragma unroll
    for (int mi = 0; mi < 4; mi++) {
      const int r0 = m0 + wm * 64 + mi * 16 + (l >> 4) * 4;
#pragma unroll
      for (int e = 0; e < 4; e++)
        out[(size_t)(r0 + e) * 1024 + c] = acc[mi][ni][e] + bo;
    }
  }
}

// ---------- launch ----------
extern "C" void kernel_launch(void* const* d_in, const int* in_sizes, int n_in,
                              void* d_out, int out_size, void* d_ws, size_t ws_size,
                              hipStream_t stream) {
  const float* x      = (const float*)d_in[0];
  const float* h0     = (const float*)d_in[1];
  const float* W_in   = (const float*)d_in[2];
  const float* b_in   = (const float*)d_in[3];
  const float* W_gate = (const float*)d_in[4];
  const float* b_gate = (const float*)d_in[5];
  const float* W_rec  = (const float*)d_in[6];
  const float* b_rec  = (const float*)d_in[7];
  const float* W_out  = (const float*)d_in[8];
  const float* b_out  = (const float*)d_in[9];
  float* outp = (float*)d_out;

  size_t off = 0;
  auto alloc = [&](size_t bytes) {
    void* p = (char*)d_ws + off;
    off += (bytes + 255) & ~(size_t)255;
    return p;
  };
  unsigned short* xb    = (unsigned short*)alloc((size_t)16777216 * 2);
  unsigned short* WinT  = (unsigned short*)alloc((size_t)3072 * 1024 * 2);
  unsigned short* WgT   = (unsigned short*)alloc((size_t)2048 * 1024 * 2);
  unsigned short* WrT   = (unsigned short*)alloc((size_t)1024 * 1024 * 2);
  unsigned short* WoT   = (unsigned short*)alloc((size_t)1024 * 1024 * 2);
  unsigned short* drive = (unsigned short*)alloc((size_t)16777216 * 2);
  unsigned short* hs    = (unsigned short*)alloc((size_t)16777216 * 2);
  unsigned int*   hx    = (unsigned int*)alloc((size_t)2 * 8192 * 4);

  // conversions / init
  k_cvt_bf16<<<16384, 256, 0, stream>>>(x, xb, 4194304);
  k_transpose_bf16<<<dim3(96, 32), 256, 0, stream>>>(W_in, WinT, 1024, 3072);
  k_transpose_bf16<<<dim3(64, 32), 256, 0, stream>>>(W_gate, WgT, 1024, 2048);
  k_transpose_bf16<<<dim3(32, 32), 256, 0, stream>>>(W_rec, WrT, 1024, 1024);
  k_transpose_bf16<<<dim3(32, 32), 256, 0, stream>>>(W_out, WoT, 1024, 1024);
  k_init_hx<<<32, 256, 0, stream>>>(h0, hx);

  // drive = silu(u)*silu(v)+w
  k_gemm_drive<<<dim3(128, 16), 256, 0, stream>>>(xb, WinT, b_in, drive);
  // sequential recurrence (R4 structure + exchange-phase instrumentation;
  // xb is dead after gemm_drive -> reused as the timing dump region)
  k_scan<<<64, 1024, 0, stream>>>(WgT, WrT, b_gate, b_rec, drive, hx, hs,
                                  outp + 16777216, (unsigned long long*)xb);
  // out = hs @ W_out + b_out
  k_gemm_out<<<dim3(128, 8), 256, 0, stream>>>(hs, WoT, b_out, outp);
}

// Round 10
// 4050.724 us; speedup vs baseline: 2.4530x; 1.8777x over previous
//
#include <hip/hip_runtime.h>

// ---------- types / helpers ----------
typedef short short8 __attribute__((ext_vector_type(8)));
typedef __bf16 bf16x8 __attribute__((ext_vector_type(8)));
typedef float f32x4 __attribute__((ext_vector_type(4)));
typedef float f32x4v __attribute__((ext_vector_type(4)));
typedef unsigned short u16x4 __attribute__((ext_vector_type(4)));
typedef unsigned int uint2v __attribute__((ext_vector_type(2)));
typedef unsigned long long u64;

__device__ __forceinline__ unsigned short f2b(float f) {
  unsigned x = __builtin_bit_cast(unsigned, f);
  x = x + 0x7fffu + ((x >> 16) & 1u);   // RNE (finite inputs)
  return (unsigned short)(x >> 16);
}
__device__ __forceinline__ float b2f(unsigned short u) {
  unsigned x = ((unsigned)u) << 16;
  return __builtin_bit_cast(float, x);
}
__device__ __forceinline__ f32x4 mfma16(short8 a, short8 b, f32x4 c) {
  return __builtin_amdgcn_mfma_f32_16x16x32_bf16(
      __builtin_bit_cast(bf16x8, a), __builtin_bit_cast(bf16x8, b), c, 0, 0, 0);
}
typedef const __attribute__((address_space(1))) void* gas_p;
typedef __attribute__((address_space(3))) void* las_p;
__device__ __forceinline__ void gload_lds16(const void* g, void* l) {
  __builtin_amdgcn_global_load_lds((gas_p)g, (las_p)l, 16, 0, 0);
}

// ---------- conversion kernels ----------
__global__ __launch_bounds__(256) void k_cvt_bf16(const float* __restrict__ in,
                                                  unsigned short* __restrict__ out,
                                                  int n4) {
  int i = blockIdx.x * 256 + threadIdx.x;
  if (i >= n4) return;
  f32x4v v = *(const f32x4v*)(in + (size_t)i * 4);
  u16x4 o;
  o[0] = f2b(v[0]); o[1] = f2b(v[1]); o[2] = f2b(v[2]); o[3] = f2b(v[3]);
  *(u16x4*)(out + (size_t)i * 4) = o;
}

// hq[b][0][i] = tag0 | bf16(h0[b][i]); hq[b][1][i] = 0  (tag 0 != any odd t)
__global__ __launch_bounds__(256) void k_init_hq(const float* __restrict__ h0,
                                                 unsigned int* __restrict__ hq) {
  int idx = blockIdx.x * 256 + threadIdx.x;
  if (idx >= 8192) return;
  int b = idx >> 10, i = idx & 1023;
  hq[(size_t)b * 2048 + i] = (unsigned int)f2b(h0[idx]);
  hq[(size_t)b * 2048 + 1024 + i] = 0u;
}

// out[c][r] = bf16(in[r][c]);  R,C multiples of 32
__global__ __launch_bounds__(256) void k_transpose_bf16(const float* __restrict__ in,
                                                        unsigned short* __restrict__ out,
                                                        int R, int C) {
  __shared__ unsigned short tile[32][33];
  int c0 = blockIdx.x * 32, r0 = blockIdx.y * 32;
  int tx = threadIdx.x & 31, ty = threadIdx.x >> 5;
#pragma unroll
  for (int i = 0; i < 4; i++) {
    int r = ty + i * 8;
    tile[r][tx] = f2b(in[(size_t)(r0 + r) * C + c0 + tx]);
  }
  __syncthreads();
#pragma unroll
  for (int i = 0; i < 4; i++) {
    int rr = ty + i * 8;
    out[(size_t)(c0 + rr) * R + r0 + tx] = tile[tx][rr];
  }
}

// ---------- GEMM1: drive = silu(u)*silu(v)+w, feats = x@W_in + b_in ----------
__global__ __launch_bounds__(256) void k_gemm_drive(const unsigned short* __restrict__ xb,
                                                    const unsigned short* __restrict__ WinT,
                                                    const float* __restrict__ b_in,
                                                    unsigned short* __restrict__ drive) {
  __shared__ unsigned short At[128 * 32];
  __shared__ unsigned short Bt[3][64 * 32];
  const int tid = threadIdx.x;
  const int w = tid >> 6, l = tid & 63;
  const int wm = w >> 1, wn = w & 1;
  const int lr = l & 15, lk = (l >> 4) * 8;
  const int m0 = blockIdx.x * 128;
  const int j0 = blockIdx.y * 64;
  f32x4 acc[3][4][2];
#pragma unroll
  for (int s = 0; s < 3; s++)
#pragma unroll
    for (int mi = 0; mi < 4; mi++)
#pragma unroll
      for (int ni = 0; ni < 2; ni++)
#pragma unroll
        for (int e = 0; e < 4; e++) acc[s][mi][ni][e] = 0.f;

  const int sr = tid >> 2;
  const int skb = (tid & 3) * 8;
  for (int kt = 0; kt < 32; kt++) {
    const int k0 = kt * 32;
    gload_lds16(xb + (size_t)(m0 + sr) * 1024 + k0 + skb, &At[w * 512]);
    gload_lds16(xb + (size_t)(m0 + 64 + sr) * 1024 + k0 + skb, &At[2048 + w * 512]);
#pragma unroll
    for (int s = 0; s < 3; s++)
      gload_lds16(WinT + (size_t)(s * 1024 + j0 + sr) * 1024 + k0 + skb, &Bt[s][w * 512]);
    __syncthreads();
    short8 Af[4], Bf[3][2];
#pragma unroll
    for (int mi = 0; mi < 4; mi++)
      Af[mi] = *(const short8*)&At[(wm * 64 + mi * 16 + lr) * 32 + lk];
#pragma unroll
    for (int s = 0; s < 3; s++)
#pragma unroll
      for (int ni = 0; ni < 2; ni++)
        Bf[s][ni] = *(const short8*)&Bt[s][(wn * 32 + ni * 16 + lr) * 32 + lk];
#pragma unroll
    for (int s = 0; s < 3; s++)
#pragma unroll
      for (int mi = 0; mi < 4; mi++)
#pragma unroll
        for (int ni = 0; ni < 2; ni++)
          acc[s][mi][ni] = mfma16(Af[mi], Bf[s][ni], acc[s][mi][ni]);
    __syncthreads();
  }
#pragma unroll
  for (int ni = 0; ni < 2; ni++) {
    const int c = j0 + wn * 32 + ni * 16 + lr;
    const float bu = b_in[c], bv = b_in[1024 + c], bw = b_in[2048 + c];
#pragma unroll
    for (int mi = 0; mi < 4; mi++) {
      const int r0 = m0 + wm * 64 + mi * 16 + (l >> 4) * 4;
#pragma unroll
      for (int e = 0; e < 4; e++) {
        float u = acc[0][mi][ni][e] + bu;
        float v = acc[1][mi][ni][e] + bv;
        float wv = acc[2][mi][ni][e] + bw;
        float su = u / (1.f + __expf(-u));
        float sv = v / (1.f + __expf(-v));
        drive[(size_t)(r0 + e) * 1024 + c] = f2b(su * sv + wv);
      }
    }
  }
}

// ---------- persistent scan kernel v10: batch-sharded rings ----------
// 256 WGs x 1024 threads (1/CU, co-resident by capacity). WG g: batch b=g>>5,
// slot s=g&31, owns features [32s,32s+32) OF BATCH b ONLY. Batches are
// independent recurrences -> 8 decoupled rings of 32 WGs; ring exchange is
// hq[b][phase][1024] tagged words ((tag<<16)|bf16, tag=t), agent-scope.
// Per ring per step: publish 32 words/WG, read 4KB/WG (2 u64 loads/lane,
// 4 poll waves) -> bypass-path traffic and straggler set both ~4-8x smaller
// than the global-ring designs (R4-R8, all ~3.5us/step).
// Waves 0-11: MFMA (mat=w>>2, kq=w&3), M=1 (batch row 0 only), B-frags in
// registers (64 VGPR/wave). Waves 12-15: pollers. tid<32: finishers.
__global__ __launch_bounds__(1024, 4) void k_scan(const unsigned short* __restrict__ WgT,
                                                  const unsigned short* __restrict__ WrT,
                                                  const float* __restrict__ b_gate,
                                                  const float* __restrict__ b_rec,
                                                  const unsigned short* __restrict__ drive,
                                                  unsigned int* __restrict__ hq,
                                                  unsigned short* __restrict__ hs,
                                                  float* __restrict__ final_h) {
  const int g = blockIdx.x;           // 0..255
  const int b = g >> 5;               // batch / ring id
  const int s = g & 31;               // slot in ring
  const int tid = threadIdx.x;        // 0..1023
  const int w = tid >> 6, l = tid & 63;

  __shared__ unsigned int tileh[512];   // h_t of batch b: bf16x2 pairs (2KB)
  __shared__ float buf[4][3][32];       // [kq][mat][col] row-0 partials

  // ---- MFMA-wave setup (w<12): B-frags -> registers (2 tiles x 8 = 64 VGPR) ----
  const int mat = w >> 2, kq = w & 3;
  const int lr = l & 15, ko = l >> 4;
  const bool av = (lr == 0);            // A row-0 carrier lanes
  short8 Breg[2][8];
  if (w < 12) {
    const unsigned short* WT = (mat == 2) ? WrT : WgT;
    const int rowbase = ((mat == 1) ? 1024 : 0) + s * 32;
#pragma unroll
    for (int tile = 0; tile < 2; ++tile)
#pragma unroll
      for (int ks = 0; ks < 8; ++ks)
        Breg[tile][ks] = *(const short8*)&WT[(size_t)(rowbase + tile * 16 + lr) * 1024 +
                                             kq * 256 + ks * 32 + ko * 8];
  }

  // ---- poller setup (waves 12-15): lane q handles u64 pairs 2q, 2q+1 ----
  const bool isld = tid >= 768;
  const int q = tid - 768;              // 0..255

  // ---- finisher setup (tid<32): feature f = tid ----
  const bool isfin = tid < 32;
  const int fcol = s * 32 + tid;        // feature within batch (tid<32)
  float bgv = 0.f, bgt = 0.f, brc = 0.f;
  if (isfin) { bgv = b_gate[fcol]; bgt = b_gate[1024 + fcol]; brc = b_rec[fcol]; }

  for (int t = 0; t < 2048; ++t) {
    const int p = t & 1;
    unsigned short dpf = 0;
    if (isfin) dpf = drive[(size_t)(b * 2048 + t) * 1024 + fcol];  // cached

    if (isld) {  // ---- poll own ring's h_t (tags == t), pack to LDS ----
      const unsigned tg = (unsigned)t;
      const u64* hb = (const u64*)(hq + (size_t)(b * 2 + p) * 1024);
      u64 v0 = 0, v1 = 0;
      unsigned pend = 3u;
      do {
        if (pend & 1u)
          v0 = __hip_atomic_load(hb + 2 * q, __ATOMIC_RELAXED,
                                 __HIP_MEMORY_SCOPE_AGENT);
        if (pend & 2u)
          v1 = __hip_atomic_load(hb + 2 * q + 1, __ATOMIC_RELAXED,
                                 __HIP_MEMORY_SCOPE_AGENT);
        unsigned np = 0;
        if ((((unsigned)v0 >> 16) != tg) | (((unsigned)(v0 >> 32) >> 16) != tg))
          np |= 1u;
        if ((((unsigned)v1 >> 16) != tg) | (((unsigned)(v1 >> 32) >> 16) != tg))
          np |= 2u;
        pend = np;
      } while (pend);
      uint2v pk;
      pk[0] = __builtin_amdgcn_perm((unsigned)(v0 >> 32), (unsigned)v0, 0x05040100u);
      pk[1] = __builtin_amdgcn_perm((unsigned)(v1 >> 32), (unsigned)v1, 0x05040100u);
      *(uint2v*)&tileh[2 * q] = pk;
    }
    __syncthreads();   // tileh(t) complete

    // ---- MFMA: 16 per wave (2 col-tiles x 8 k-slices), row 0 = batch ----
    if (w < 12) {
      f32x4 a0, a1;
#pragma unroll
      for (int e = 0; e < 4; ++e) { a0[e] = 0.f; a1[e] = 0.f; }
      const char* base = (const char*)tileh + kq * 512 + ko * 16;
#pragma unroll
      for (int ks = 0; ks < 8; ++ks) {
        short8 Af;
#pragma unroll
        for (int e = 0; e < 8; ++e) Af[e] = 0;
        if (av) Af = *(const short8*)(base + ks * 64);
        a0 = mfma16(Af, Breg[0][ks], a0);
        a1 = mfma16(Af, Breg[1][ks], a1);
      }
      if (l < 16) {   // D row 0 lives in lanes 0-15, reg 0
        buf[kq][mat][l] = a0[0];
        buf[kq][mat][16 + l] = a1[0];
      }
    }
    __syncthreads();   // buf complete; tileh free for t+1

    // ---- finisher: K-quarter reduce + gate math + tagged publish ----
    if (isfin) {
      const float gv = ((buf[0][0][tid] + buf[1][0][tid]) +
                        (buf[2][0][tid] + buf[3][0][tid])) + bgv;
      const float gt = ((buf[0][1][tid] + buf[1][1][tid]) +
                        (buf[2][1][tid] + buf[3][1][tid])) + bgt;
      const float rc = ((buf[0][2][tid] + buf[1][2][tid]) +
                        (buf[2][2][tid] + buf[3][2][tid])) + brc;
      const float sgv = 1.f / (1.f + __expf(-gv));
      const float sgt = 1.f / (1.f + __expf(-gt));
      const float gate = sgv * gt * sgt;  // sigmoid(gv) * silu(gt)
      const float nh = gate * rc + (1.f - gate) * b2f(dpf);
      const unsigned short nhb = f2b(nh);
      __hip_atomic_store(hq + (size_t)(b * 2 + (p ^ 1)) * 1024 + fcol,
                         (((unsigned)(t + 1)) << 16) | (unsigned)nhb,
                         __ATOMIC_RELAXED, __HIP_MEMORY_SCOPE_AGENT);
      hs[(size_t)(b * 2048 + t) * 1024 + fcol] = nhb;
      if (t == 2047) final_h[b * 1024 + fcol] = nh;
    }
    // no 3rd barrier: finisher work overlaps ring-mates' next poll
  }
}

// ---------- GEMM3: out = hs @ W_out + b_out ----------
__global__ __launch_bounds__(256) void k_gemm_out(const unsigned short* __restrict__ hs,
                                                  const unsigned short* __restrict__ WoT,
                                                  const float* __restrict__ b_out,
                                                  float* __restrict__ out) {
  __shared__ unsigned short At[128 * 32];
  __shared__ unsigned short Bt[128 * 32];
  const int tid = threadIdx.x;
  const int w = tid >> 6, l = tid & 63;
  const int wm = w >> 1, wn = w & 1;
  const int lr = l & 15, lk = (l >> 4) * 8;
  const int m0 = blockIdx.x * 128;
  const int n0 = blockIdx.y * 128;
  f32x4 acc[4][4];
#pragma unroll
  for (int mi = 0; mi < 4; mi++)
#pragma unroll
    for (int ni = 0; ni < 4; ni++)
#pragma unroll
      for (int e = 0; e < 4; e++) acc[mi][ni][e] = 0.f;

  const int sr = tid >> 2;
  const int skb = (tid & 3) * 8;
  for (int kt = 0; kt < 32; kt++) {
    const int k0 = kt * 32;
    gload_lds16(hs + (size_t)(m0 + sr) * 1024 + k0 + skb, &At[w * 512]);
    gload_lds16(hs + (size_t)(m0 + 64 + sr) * 1024 + k0 + skb, &At[2048 + w * 512]);
    gload_lds16(WoT + (size_t)(n0 + sr) * 1024 + k0 + skb, &Bt[w * 512]);
    gload_lds16(WoT + (size_t)(n0 + 64 + sr) * 1024 + k0 + skb, &Bt[2048 + w * 512]);
    __syncthreads();
    short8 Af[4], Bf[4];
#pragma unroll
    for (int mi = 0; mi < 4; mi++)
      Af[mi] = *(const short8*)&At[(wm * 64 + mi * 16 + lr) * 32 + lk];
#pragma unroll
    for (int ni = 0; ni < 4; ni++)
      Bf[ni] = *(const short8*)&Bt[(wn * 64 + ni * 16 + lr) * 32 + lk];
#pragma unroll
    for (int mi = 0; mi < 4; mi++)
#pragma unroll
      for (int ni = 0; ni < 4; ni++)
        acc[mi][ni] = mfma16(Af[mi], Bf[ni], acc[mi][ni]);
    __syncthreads();
  }
#pragma unroll
  for (int ni = 0; ni < 4; ni++) {
    const int c = n0 + wn * 64 + ni * 16 + lr;
    const float bo = b_out[c];
#pragma unroll
    for (int mi = 0; mi < 4; mi++) {
      const int r0 = m0 + wm * 64 + mi * 16 + (l >> 4) * 4;
#pragma unroll
      for (int e = 0; e < 4; e++)
        out[(size_t)(r0 + e) * 1024 + c] = acc[mi][ni][e] + bo;
    }
  }
}

// ---------- launch ----------
extern "C" void kernel_launch(void* const* d_in, const int* in_sizes, int n_in,
                              void* d_out, int out_size, void* d_ws, size_t ws_size,
                              hipStream_t stream) {
  const float* x      = (const float*)d_in[0];
  const float* h0     = (const float*)d_in[1];
  const float* W_in   = (const float*)d_in[2];
  const float* b_in   = (const float*)d_in[3];
  const float* W_gate = (const float*)d_in[4];
  const float* b_gate = (const float*)d_in[5];
  const float* W_rec  = (const float*)d_in[6];
  const float* b_rec  = (const float*)d_in[7];
  const float* W_out  = (const float*)d_in[8];
  const float* b_out  = (const float*)d_in[9];
  float* outp = (float*)d_out;

  size_t off = 0;
  auto alloc = [&](size_t bytes) {
    void* p = (char*)d_ws + off;
    off += (bytes + 255) & ~(size_t)255;
    return p;
  };
  unsigned short* xb    = (unsigned short*)alloc((size_t)16777216 * 2);
  unsigned short* WinT  = (unsigned short*)alloc((size_t)3072 * 1024 * 2);
  unsigned short* WgT   = (unsigned short*)alloc((size_t)2048 * 1024 * 2);
  unsigned short* WrT   = (unsigned short*)alloc((size_t)1024 * 1024 * 2);
  unsigned short* WoT   = (unsigned short*)alloc((size_t)1024 * 1024 * 2);
  unsigned short* drive = (unsigned short*)alloc((size_t)16777216 * 2);
  unsigned short* hs    = (unsigned short*)alloc((size_t)16777216 * 2);
  unsigned int*   hq    = (unsigned int*)alloc((size_t)8 * 2 * 1024 * 4);  // 64KB

  // conversions / init
  k_cvt_bf16<<<16384, 256, 0, stream>>>(x, xb, 4194304);
  k_transpose_bf16<<<dim3(96, 32), 256, 0, stream>>>(W_in, WinT, 1024, 3072);
  k_transpose_bf16<<<dim3(64, 32), 256, 0, stream>>>(W_gate, WgT, 1024, 2048);
  k_transpose_bf16<<<dim3(32, 32), 256, 0, stream>>>(W_rec, WrT, 1024, 1024);
  k_transpose_bf16<<<dim3(32, 32), 256, 0, stream>>>(W_out, WoT, 1024, 1024);
  k_init_hq<<<32, 256, 0, stream>>>(h0, hq);

  // drive = silu(u)*silu(v)+w
  k_gemm_drive<<<dim3(128, 16), 256, 0, stream>>>(xb, WinT, b_in, drive);
  // sequential recurrence: 8 independent batch rings x 32 WGs
  k_scan<<<256, 1024, 0, stream>>>(WgT, WrT, b_gate, b_rec, drive, hq, hs,
                                   outp + 16777216);
  // out = hs @ W_out + b_out
  k_gemm_out<<<dim3(128, 8), 256, 0, stream>>>(hs, WoT, b_out, outp);
}